// Round 10
// baseline (193.789 us; speedup 1.0000x reference)
//
#include <hip/hip_runtime.h>
#include <math.h>

#define BB 2
#define TT 2048
#define DD 1024
#define NH 16
#define HDD 64

typedef __attribute__((ext_vector_type(8))) short v8s;     // 8 bf16 in 4 VGPRs
typedef __attribute__((ext_vector_type(4))) short v4s;     // 4 bf16 in 2 VGPRs
typedef __attribute__((ext_vector_type(4))) float f32x4;   // MFMA C/D

__device__ __forceinline__ unsigned short f2bf(float f) {
    union { float f; unsigned int u; } c; c.f = f;
    unsigned int r = c.u + 0x7FFF + ((c.u >> 16) & 1);     // RNE
    return (unsigned short)(r >> 16);
}

// pack 4 floats -> 4 bf16 (RNE).  HW v_cvt_pk_bf16_f32 when available.
__device__ __forceinline__ v4s pack_bf16x4(float a, float b, float c, float d) {
#if __has_builtin(__builtin_amdgcn_cvt_pk_bf16_f32)
    auto lo = __builtin_amdgcn_cvt_pk_bf16_f32(a, b);      // 2 bf16 in 4B
    auto hi = __builtin_amdgcn_cvt_pk_bf16_f32(c, d);
    union { v4s v; struct { decltype(lo) l; decltype(hi) h; } p; } u;
    u.p.l = lo; u.p.h = hi;
    return u.v;
#else
    v4s r;
    r[0] = (short)f2bf(a); r[1] = (short)f2bf(b);
    r[2] = (short)f2bf(c); r[3] = (short)f2bf(d);
    return r;
#endif
}

// K=16 bf16 MFMA (v_mfma_f32_16x16x16_bf16: A/B = 4 bf16, C/D = 4 f32).
__device__ __forceinline__ f32x4 mfma16x16x16bf16(v4s a, v4s b, f32x4 c) {
#if __has_builtin(__builtin_amdgcn_mfma_f32_16x16x16bf16_1k)
    return __builtin_amdgcn_mfma_f32_16x16x16bf16_1k(a, b, c, 0, 0, 0);
#else
    f32x4 d;
    asm("v_mfma_f32_16x16x16_bf16 %0, %1, %2, %0"
        : "=v"(d) : "v"(a), "v"(b), "0"(c));
    return d;
#endif
}

// ============================================================================
// Cast fp32 -> bf16 for x, Wq, Wk, Wv, Wo (blockIdx.y selects tensor).
// (unchanged)
// ============================================================================
__global__ __launch_bounds__(256) void cast5_kernel(
    const float* __restrict__ x, const float* __restrict__ wq,
    const float* __restrict__ wk, const float* __restrict__ wv,
    const float* __restrict__ wo,
    unsigned short* __restrict__ xo, unsigned short* __restrict__ wqo,
    unsigned short* __restrict__ wko, unsigned short* __restrict__ wvo,
    unsigned short* __restrict__ woo)
{
    const float* s; unsigned short* d; int n4;
    switch (blockIdx.y) {
        case 0: s = x;  d = xo;  n4 = BB * TT * DD / 4; break;
        case 1: s = wq; d = wqo; n4 = DD * DD / 4; break;
        case 2: s = wk; d = wko; n4 = DD * DD / 4; break;
        case 3: s = wv; d = wvo; n4 = DD * DD / 4; break;
        default: s = wo; d = woo; n4 = DD * DD / 4; break;
    }
    int i = blockIdx.x * 256 + threadIdx.x;
    if (i < n4) {
        float4 v = ((const float4*)s)[i];
        ushort4 o;
        o.x = f2bf(v.x); o.y = f2bf(v.y); o.z = f2bf(v.z); o.w = f2bf(v.w);
        ((ushort4*)d)[i] = o;
    }
}

// ============================================================================
// QKV projection: bf16 MFMA B^T GEMM, 128x128 tile, BK=32.
// R10: VGPR two-phase staging — global->regs at iter top, MFMA compute,
// ds_write regs->other buffer AFTER compute (vmcnt wait lands post-compute),
// barrier drains only lgkm.  (R6's global_load_lds dbuf still paid the full
// vmcnt(0) drain at the same-iteration barrier.)
// ============================================================================
__global__ __launch_bounds__(256) void qkv_mfma(
    const unsigned short* __restrict__ x,
    const unsigned short* __restrict__ wq, const unsigned short* __restrict__ wk,
    const unsigned short* __restrict__ wv,
    unsigned short* __restrict__ qo, unsigned short* __restrict__ ko,
    unsigned short* __restrict__ vo)
{
    __shared__ unsigned short SMEM[16384];    // 32 KB

    const int tid = threadIdx.x;
    const int lane = tid & 63;
    const int wid = tid >> 6;
    const int l15 = lane & 15, quad = lane >> 4;

    const int m0 = blockIdx.x << 7;
    const int ny = blockIdx.y;
    const int which = ny >> 3;                // 0=q 1=k 2=v
    const int n0 = (ny & 7) << 7;
    const unsigned short* W = (which == 0) ? wq : (which == 1) ? wk : wv;

    const int wm = (wid >> 1) << 6;
    const int wn = (wid & 1) << 6;

    const int f0 = (wid << 11) + (lane << 4);
    const int row0 = f0 >> 6, cs0 = (f0 & 63) >> 1;
    const int f1 = f0 + 1024;
    const int row1 = f1 >> 6, cs1 = (f1 & 63) >> 1;

    char* const smem = (char*)SMEM;

    uint4 xa0, xa1, wb0, wb1;                 // staging regs

#define QKV_LOAD(k0)                                                           \
    do {                                                                       \
        xa0 = *(const uint4*)&x[(size_t)(m0 + row0) * DD + (k0) + cs0];        \
        xa1 = *(const uint4*)&x[(size_t)(m0 + row1) * DD + (k0) + cs1];        \
        wb0 = *(const uint4*)&W[(size_t)(n0 + row0) * DD + (k0) + cs0];        \
        wb1 = *(const uint4*)&W[(size_t)(n0 + row1) * DD + (k0) + cs1];        \
    } while (0)

#define QKV_WRITE(buf)                                                         \
    do {                                                                       \
        *(uint4*)(smem + (buf) * 8192 + f0) = xa0;                             \
        *(uint4*)(smem + (buf) * 8192 + f1) = xa1;                             \
        *(uint4*)(smem + 16384 + (buf) * 8192 + f0) = wb0;                     \
        *(uint4*)(smem + 16384 + (buf) * 8192 + f1) = wb1;                     \
    } while (0)

    f32x4 acc[4][4] = {};

    QKV_LOAD(0);
    QKV_WRITE(0);
    __syncthreads();

    int cur = 0;
    for (int k0 = 0; k0 < DD; k0 += 32) {
        const bool pre = (k0 + 32 < DD);
        if (pre) QKV_LOAD(k0 + 32);           // loads land during compute

        const char* Ab = smem + cur * 8192;
        const char* Bb = smem + 16384 + cur * 8192;
        v8s af[4], bf[4];
#pragma unroll
        for (int i = 0; i < 4; ++i)
            af[i] = *(const v8s*)(Ab + (wm + (i << 4) + l15) * 64 + (quad << 4));
#pragma unroll
        for (int j = 0; j < 4; ++j)
            bf[j] = *(const v8s*)(Bb + (wn + (j << 4) + l15) * 64 + (quad << 4));
#pragma unroll
        for (int i = 0; i < 4; ++i)
#pragma unroll
            for (int j = 0; j < 4; ++j)
                acc[i][j] = __builtin_amdgcn_mfma_f32_16x16x32_bf16(af[i], bf[j], acc[i][j], 0, 0, 0);

        if (pre) QKV_WRITE(cur ^ 1);          // vmcnt wait here, post-compute
        __syncthreads();
        cur ^= 1;
    }
#undef QKV_LOAD
#undef QKV_WRITE

    if (which == 2) {
        // v transposed: (B,H,HD,T); lane's 4 acc rows = consecutive t -> 8B store
#pragma unroll
        for (int i = 0; i < 4; ++i)
#pragma unroll
            for (int j = 0; j < 4; ++j) {
                const int n = n0 + wn + (j << 4) + l15;
                const int h = n >> 6, hd = n & 63;
                const int mb = m0 + wm + (i << 4) + (quad << 2);
                const int b = mb >> 11, t = mb & 2047;
                ushort4 pk;
                pk.x = f2bf(acc[i][j][0]); pk.y = f2bf(acc[i][j][1]);
                pk.z = f2bf(acc[i][j][2]); pk.w = f2bf(acc[i][j][3]);
                *(ushort4*)&vo[((((size_t)(b * NH + h) << 6) + hd) << 11) + t] = pk;
            }
    } else {
        unsigned short* outp = (which == 0) ? qo : ko;
        const float sc = (which == 1) ? 0.125f : 1.0f;
#pragma unroll
        for (int p = 0; p < 2; ++p) {
            __syncthreads();
            if ((wid >> 1) == p) {
#pragma unroll
                for (int i = 0; i < 4; ++i)
#pragma unroll
                    for (int j = 0; j < 4; ++j)
#pragma unroll
                        for (int r = 0; r < 4; ++r) {
                            const int row = (i << 4) + (quad << 2) + r;
                            SMEM[row * 136 + wn + (j << 4) + l15] = f2bf(acc[i][j][r] * sc);
                        }
            }
            __syncthreads();
            const int rr = tid >> 2;
            const int cg = (tid & 3) << 5;
            const int m = m0 + (p << 6) + rr;
            const int b = m >> 11, t = m & 2047;
#pragma unroll
            for (int k2 = 0; k2 < 4; ++k2) {
                const int n = n0 + cg + (k2 << 3);
                const int h = n >> 6, hd = n & 63;
                const uint4 val = *(const uint4*)&SMEM[rr * 136 + cg + (k2 << 3)];
                *(uint4*)&outp[(((size_t)(b * NH + h) * TT + t) << 6) + hd] = val;
            }
        }
    }
}

// ============================================================================
// Flash attention, bf16 MFMA, S^T formulation + XCD swizzle + single-barrier
// double-buffered K/V staging + unpaired longest-first grid (R9).
// R10: Vts column XOR-swizzle by row-bit-3 (col ^= (row&8)<<2, a 32-ushort
//   flip).  Stride-72 bank map: K/Q b128 reads & staging writes are uniform
//   (8 dw/bank, ideal) but Vt v4s reads were 2-way (4*l15 repeats mod 32 for
//   l15 vs l15+8 -> 16 dw on 2 banks).  The swizzle puts l15<8 / l15>=8 on
//   disjoint bank sets -> 4 dw/bank ideal.  Writes stay uniform: bit3 of the
//   staging row is wave-uniform.  (R8's stride-80 attempt made the base term
//   4-way -> conflicts doubled; this targets only the measured offender.)
// ============================================================================
__global__ __launch_bounds__(256) void attn_mfma(
    const unsigned short* __restrict__ q, const unsigned short* __restrict__ k,
    const unsigned short* __restrict__ vt, unsigned short* __restrict__ ctx)
{
    __shared__ unsigned short Qs[64][72];
    __shared__ unsigned short Ks[2][64][72];
    __shared__ unsigned short Vts[2][64][72];

    const int tid = threadIdx.x;
    const int lane = tid & 63;
    const int wid = tid >> 6;
    const int l15 = lane & 15, quad = lane >> 4;

    // bx = bh (XCD-locality: lin = bh + 32*by => lin%8 = bh%8), by -> q-tile
    const int bh = blockIdx.x;
    const int qt = 31 - (int)blockIdx.y;      // longest blocks dispatch first
    const int q0 = qt << 6;
    const int qrow = q0 + (wid << 4) + l15;   // this lane's q-row

    const unsigned short* qb = q + (size_t)bh * TT * HDD;
    const unsigned short* kb = k + (size_t)bh * TT * HDD;
    const unsigned short* vb = vt + (size_t)bh * HDD * TT;   // (HD, T)
    unsigned short* cb = ctx + (size_t)bh * TT * HDD;

    const int cr = tid >> 3;            // staging row 0..31 (x2 rounds)
    const int cc = (tid & 7) << 3;      // staging col (ushort), 16B chunks
    const int vsw = (cr & 8) << 2;      // Vts write swizzle (row-bit-3, both rows)
    const int ccv = cc ^ vsw;
    const int rsw = (l15 & 8) << 2;     // Vts read swizzle for this lane

    // Q tile + K/V tile 0 -> LDS
#pragma unroll
    for (int u = 0; u < 2; ++u) {
        const int r = cr + (u << 5);
        *(uint4*)&Qs[r][cc] = *(const uint4*)&qb[(size_t)(q0 + r) * HDD + cc];
    }
    {
        uint4 k0r = *(const uint4*)&kb[(size_t)cr * HDD + cc];
        uint4 k1r = *(const uint4*)&kb[(size_t)(cr + 32) * HDD + cc];
        uint4 v0r = *(const uint4*)&vb[((size_t)cr << 11) + cc];
        uint4 v1r = *(const uint4*)&vb[((size_t)(cr + 32) << 11) + cc];
        *(uint4*)&Ks[0][cr][cc] = k0r;
        *(uint4*)&Ks[0][cr + 32][cc] = k1r;
        *(uint4*)&Vts[0][cr][ccv] = v0r;
        *(uint4*)&Vts[0][cr + 32][ccv] = v1r;
    }
    __syncthreads();

    // Q B-frags, wave-resident for the k-loop
    v8s qf[2];
#pragma unroll
    for (int c = 0; c < 2; ++c)
        qf[c] = *(const v8s*)&Qs[(wid << 4) + l15][(c << 5) + (quad << 3)];

    float m_i = -INFINITY, l_i = 0.f;
    f32x4 o[4] = {};                    // O^T: d = m*16 + quad*4 + r, col q=l15

    for (int jt = 0; jt <= qt; ++jt) {
        const int cur = jt & 1;

        // issue global loads for tile jt+1 (land during compute below)
        uint4 k0r, k1r, v0r, v1r;
        const bool pre = (jt < qt);
        if (pre) {
            const int kn = (jt + 1) << 6;
            k0r = *(const uint4*)&kb[(size_t)(kn + cr) * HDD + cc];
            k1r = *(const uint4*)&kb[(size_t)(kn + cr + 32) * HDD + cc];
            v0r = *(const uint4*)&vb[((size_t)cr << 11) + kn + cc];
            v1r = *(const uint4*)&vb[((size_t)(cr + 32) << 11) + kn + cc];
        }

        const int k0 = jt << 6;

        // S^T = K . Q^T : St[k = m*16+quad*4+r][q = l15]  (K pre-scaled)
        f32x4 s[4] = {};
#pragma unroll
        for (int m = 0; m < 4; ++m) {
            const v8s kf0 = *(const v8s*)&Ks[cur][(m << 4) + l15][quad << 3];
            const v8s kf1 = *(const v8s*)&Ks[cur][(m << 4) + l15][32 + (quad << 3)];
            s[m] = __builtin_amdgcn_mfma_f32_16x16x32_bf16(kf0, qf[0], s[m], 0, 0, 0);
            s[m] = __builtin_amdgcn_mfma_f32_16x16x32_bf16(kf1, qf[1], s[m], 0, 0, 0);
        }

        if (jt == qt) {                 // causal mask, diagonal tile only
#pragma unroll
            for (int m = 0; m < 4; ++m) {
                const int kc = k0 + (m << 4) + (quad << 2);
#pragma unroll
                for (int r = 0; r < 4; ++r)
                    if (kc + r > qrow) s[m][r] = -INFINITY;
            }
        }

        // online softmax: one q-row per lane (16 in-reg values, 2 shfl)
        float mx = fmaxf(fmaxf(s[0][0], s[0][1]), fmaxf(s[0][2], s[0][3]));
        mx = fmaxf(mx, fmaxf(fmaxf(s[1][0], s[1][1]), fmaxf(s[1][2], s[1][3])));
        mx = fmaxf(mx, fmaxf(fmaxf(s[2][0], s[2][1]), fmaxf(s[2][2], s[2][3])));
        mx = fmaxf(mx, fmaxf(fmaxf(s[3][0], s[3][1]), fmaxf(s[3][2], s[3][3])));
        mx = fmaxf(mx, __shfl_xor(mx, 16));
        mx = fmaxf(mx, __shfl_xor(mx, 32));
        const float m_new = fmaxf(m_i, mx);
        const float alpha = __expf(m_i - m_new);
        m_i = m_new;

        float sum = 0.f;
        v4s pf[4];
#pragma unroll
        for (int m = 0; m < 4; ++m) {
            const float p0 = __expf(s[m][0] - m_new);
            const float p1 = __expf(s[m][1] - m_new);
            const float p2 = __expf(s[m][2] - m_new);
            const float p3 = __expf(s[m][3] - m_new);
            sum += (p0 + p1) + (p2 + p3);
            pf[m] = pack_bf16x4(p0, p1, p2, p3);
        }
        sum += __shfl_xor(sum, 16);
        sum += __shfl_xor(sum, 32);
        l_i = l_i * alpha + sum;

#pragma unroll
        for (int m = 0; m < 4; ++m)
#pragma unroll
            for (int r = 0; r < 4; ++r)
                o[m][r] *= alpha;

        // O^T += Vt . P^T   (A = Vt 16x16 chunk (swizzled read), B = P^T regs)
#pragma unroll
        for (int m = 0; m < 4; ++m)
#pragma unroll
            for (int c = 0; c < 4; ++c) {
                const v4s vf = *(const v4s*)&Vts[cur][(m << 4) + l15]
                                                    [(((c << 4) + (quad << 2)) ^ rsw)];
                o[m] = mfma16x16x16bf16(vf, pf[c], o[m]);
            }

        // publish tile jt+1 into the other buffer
        if (pre) {
            const int nxt = cur ^ 1;
            *(uint4*)&Ks[nxt][cr][cc] = k0r;
            *(uint4*)&Ks[nxt][cr + 32][cc] = k1r;
            *(uint4*)&Vts[nxt][cr][ccv] = v0r;
            *(uint4*)&Vts[nxt][cr + 32][ccv] = v1r;
        }
        __syncthreads();
    }

    // normalize + store: ctx[q][d], d = m*16 + quad*4 + r (8B stores)
    const float linv = 1.f / l_i;
#pragma unroll
    for (int m = 0; m < 4; ++m) {
        ushort4 st;
        st.x = f2bf(o[m][0] * linv); st.y = f2bf(o[m][1] * linv);
        st.z = f2bf(o[m][2] * linv); st.w = f2bf(o[m][3] * linv);
        *(ushort4*)&cb[((size_t)qrow << 6) + (m << 4) + (quad << 2)] = st;
    }
}

// ============================================================================
// Output projection: R10 VGPR two-phase staging (same as qkv).
// ============================================================================
__global__ __launch_bounds__(256) void oproj_mfma(
    const unsigned short* __restrict__ c, const unsigned short* __restrict__ wo,
    const float* __restrict__ bo, float* __restrict__ out)
{
    __shared__ unsigned short SMEM[16384];    // 32 KB

    const int tid = threadIdx.x;
    const int lane = tid & 63;
    const int wid = tid >> 6;
    const int l15 = lane & 15, quad = lane >> 4;

    const int m0 = blockIdx.x << 7;
    const int n0 = blockIdx.y << 7;
    const int wm = (wid >> 1) << 6, wn = (wid & 1) << 6;

    const int f0 = (wid << 11) + (lane << 4);
    const int row0 = f0 >> 6, cs0 = (f0 & 63) >> 1;
    const int f1 = f0 + 1024;
    const int row1 = f1 >> 6, cs1 = (f1 & 63) >> 1;

    char* const smem = (char*)SMEM;

    uint4 xa0, xa1, wb0, wb1;

#define OP_LOAD(k0)                                                            \
    do {                                                                       \
        xa0 = *(const uint4*)&c[(size_t)(m0 + row0) * DD + (k0) + cs0];        \
        xa1 = *(const uint4*)&c[(size_t)(m0 + row1) * DD + (k0) + cs1];        \
        wb0 = *(const uint4*)&wo[(size_t)(n0 + row0) * DD + (k0) + cs0];       \
        wb1 = *(const uint4*)&wo[(size_t)(n0 + row1) * DD + (k0) + cs1];       \
    } while (0)

#define OP_WRITE(buf)                                                          \
    do {                                                                       \
        *(uint4*)(smem + (buf) * 8192 + f0) = xa0;                             \
        *(uint4*)(smem + (buf) * 8192 + f1) = xa1;                             \
        *(uint4*)(smem + 16384 + (buf) * 8192 + f0) = wb0;                     \
        *(uint4*)(smem + 16384 + (buf) * 8192 + f1) = wb1;                     \
    } while (0)

    f32x4 acc[4][4] = {};

    OP_LOAD(0);
    OP_WRITE(0);
    __syncthreads();

    int cur = 0;
    for (int k0 = 0; k0 < DD; k0 += 32) {
        const bool pre = (k0 + 32 < DD);
        if (pre) OP_LOAD(k0 + 32);

        const char* Ab = smem + cur * 8192;
        const char* Bb = smem + 16384 + cur * 8192;
        v8s af[4], bf[4];
#pragma unroll
        for (int i = 0; i < 4; ++i)
            af[i] = *(const v8s*)(Ab + (wm + (i << 4) + l15) * 64 + (quad << 4));
#pragma unroll
        for (int j = 0; j < 4; ++j)
            bf[j] = *(const v8s*)(Bb + (wn + (j << 4) + l15) * 64 + (quad << 4));
#pragma unroll
        for (int i = 0; i < 4; ++i)
#pragma unroll
            for (int j = 0; j < 4; ++j)
                acc[i][j] = __builtin_amdgcn_mfma_f32_16x16x32_bf16(af[i], bf[j], acc[i][j], 0, 0, 0);

        if (pre) OP_WRITE(cur ^ 1);
        __syncthreads();
        cur ^= 1;
    }
#undef OP_LOAD
#undef OP_WRITE

#pragma unroll
    for (int j = 0; j < 4; ++j) {
        const int n = n0 + wn + (j << 4) + l15;
        const float bias = bo[n];
#pragma unroll
        for (int i = 0; i < 4; ++i) {
            const int mb = m0 + wm + (i << 4) + (quad << 2);
#pragma unroll
            for (int r = 0; r < 4; ++r)
                out[(size_t)(mb + r) * DD + n] = acc[i][j][r] + bias;
        }
    }
}

extern "C" void kernel_launch(void* const* d_in, const int* in_sizes, int n_in,
                              void* d_out, int out_size, void* d_ws, size_t ws_size,
                              hipStream_t stream) {
    const float* x  = (const float*)d_in[0];
    const float* Wq = (const float*)d_in[1];
    const float* Wk = (const float*)d_in[2];
    const float* Wv = (const float*)d_in[3];
    const float* Wo = (const float*)d_in[4];
    const float* bo = (const float*)d_in[5];
    float* out = (float*)d_out;

    const size_t NX = (size_t)BB * TT * DD;
    const size_t NW = (size_t)DD * DD;

    unsigned short* xb  = (unsigned short*)d_ws;
    unsigned short* wqb = xb + NX;
    unsigned short* wkb = wqb + NW;
    unsigned short* wvb = wkb + NW;
    unsigned short* wob = wvb + NW;
    unsigned short* qb  = wob + NW;
    unsigned short* kb  = qb + NX;
    unsigned short* vtb = kb + NX;
    unsigned short* cbuf = vtb + NX;

    cast5_kernel<<<dim3(4096, 5), 256, 0, stream>>>(x, Wq, Wk, Wv, Wo,
                                                    xb, wqb, wkb, wvb, wob);
    qkv_mfma<<<dim3(32, 24), 256, 0, stream>>>(xb, wqb, wkb, wvb, qb, kb, vtb);
    attn_mfma<<<dim3(32, 32), 256, 0, stream>>>(qb, kb, vtb, cbuf);
    oproj_mfma<<<dim3(32, 8), 256, 0, stream>>>(cbuf, wob, bo, out);
}

// Round 11
// 182.406 us; speedup vs baseline: 1.0624x; 1.0624x over previous
//
#include <hip/hip_runtime.h>
#include <math.h>

#define BB 2
#define TT 2048
#define DD 1024
#define NH 16
#define HDD 64

typedef __attribute__((ext_vector_type(8))) short v8s;     // 8 bf16 in 4 VGPRs
typedef __attribute__((ext_vector_type(4))) short v4s;     // 4 bf16 in 2 VGPRs
typedef __attribute__((ext_vector_type(4))) float f32x4;   // MFMA C/D

__device__ __forceinline__ unsigned short f2bf(float f) {
    union { float f; unsigned int u; } c; c.f = f;
    unsigned int r = c.u + 0x7FFF + ((c.u >> 16) & 1);     // RNE
    return (unsigned short)(r >> 16);
}

// pack 4 floats -> 4 bf16 (RNE).  HW v_cvt_pk_bf16_f32 when available.
__device__ __forceinline__ v4s pack_bf16x4(float a, float b, float c, float d) {
#if __has_builtin(__builtin_amdgcn_cvt_pk_bf16_f32)
    auto lo = __builtin_amdgcn_cvt_pk_bf16_f32(a, b);      // 2 bf16 in 4B
    auto hi = __builtin_amdgcn_cvt_pk_bf16_f32(c, d);
    union { v4s v; struct { decltype(lo) l; decltype(hi) h; } p; } u;
    u.p.l = lo; u.p.h = hi;
    return u.v;
#else
    v4s r;
    r[0] = (short)f2bf(a); r[1] = (short)f2bf(b);
    r[2] = (short)f2bf(c); r[3] = (short)f2bf(d);
    return r;
#endif
}

__device__ __forceinline__ void gload_lds16(const void* g, void* l) {
    __builtin_amdgcn_global_load_lds(
        (const __attribute__((address_space(1))) void*)g,
        (__attribute__((address_space(3))) void*)l, 16, 0, 0);
}

// K=16 bf16 MFMA (v_mfma_f32_16x16x16_bf16: A/B = 4 bf16, C/D = 4 f32).
__device__ __forceinline__ f32x4 mfma16x16x16bf16(v4s a, v4s b, f32x4 c) {
#if __has_builtin(__builtin_amdgcn_mfma_f32_16x16x16bf16_1k)
    return __builtin_amdgcn_mfma_f32_16x16x16bf16_1k(a, b, c, 0, 0, 0);
#else
    f32x4 d;
    asm("v_mfma_f32_16x16x16_bf16 %0, %1, %2, %0"
        : "=v"(d) : "v"(a), "v"(b), "0"(c));
    return d;
#endif
}

// ============================================================================
// Cast fp32 -> bf16 for x, Wq, Wk, Wv, Wo (blockIdx.y selects tensor).
// (unchanged)
// ============================================================================
__global__ __launch_bounds__(256) void cast5_kernel(
    const float* __restrict__ x, const float* __restrict__ wq,
    const float* __restrict__ wk, const float* __restrict__ wv,
    const float* __restrict__ wo,
    unsigned short* __restrict__ xo, unsigned short* __restrict__ wqo,
    unsigned short* __restrict__ wko, unsigned short* __restrict__ wvo,
    unsigned short* __restrict__ woo)
{
    const float* s; unsigned short* d; int n4;
    switch (blockIdx.y) {
        case 0: s = x;  d = xo;  n4 = BB * TT * DD / 4; break;
        case 1: s = wq; d = wqo; n4 = DD * DD / 4; break;
        case 2: s = wk; d = wko; n4 = DD * DD / 4; break;
        case 3: s = wv; d = wvo; n4 = DD * DD / 4; break;
        default: s = wo; d = woo; n4 = DD * DD / 4; break;
    }
    int i = blockIdx.x * 256 + threadIdx.x;
    if (i < n4) {
        float4 v = ((const float4*)s)[i];
        ushort4 o;
        o.x = f2bf(v.x); o.y = f2bf(v.y); o.z = f2bf(v.z); o.w = f2bf(v.w);
        ((ushort4*)d)[i] = o;
    }
}

// ============================================================================
// QKV projection: REVERTED to R6's global_load_lds double-buffered K-loop
// (R10's VGPR two-phase staging put the vmcnt wait on the per-iter critical
// path and regressed 45 -> 51 µs; direct-to-LDS async staging measured best).
// ============================================================================
__global__ __launch_bounds__(256) void qkv_mfma(
    const unsigned short* __restrict__ x,
    const unsigned short* __restrict__ wq, const unsigned short* __restrict__ wk,
    const unsigned short* __restrict__ wv,
    unsigned short* __restrict__ qo, unsigned short* __restrict__ ko,
    unsigned short* __restrict__ vo)
{
    __shared__ unsigned short SMEM[16384];    // 32 KB

    const int tid = threadIdx.x;
    const int lane = tid & 63;
    const int wid = tid >> 6;
    const int l15 = lane & 15, quad = lane >> 4;

    const int m0 = blockIdx.x << 7;
    const int ny = blockIdx.y;
    const int which = ny >> 3;                // 0=q 1=k 2=v
    const int n0 = (ny & 7) << 7;
    const unsigned short* W = (which == 0) ? wq : (which == 1) ? wk : wv;

    const int wm = (wid >> 1) << 6;
    const int wn = (wid & 1) << 6;

    const int f0 = (wid << 11) + (lane << 4);
    const int row0 = f0 >> 6, cs0 = (f0 & 63) >> 1;
    const int f1 = f0 + 1024;
    const int row1 = f1 >> 6, cs1 = (f1 & 63) >> 1;

    char* const smem = (char*)SMEM;

#define QKV_STAGE(k0, buf)                                                     \
    do {                                                                       \
        gload_lds16(&x[(size_t)(m0 + row0) * DD + (k0) + cs0],                 \
                    smem + (buf) * 8192 + f0);                                 \
        gload_lds16(&x[(size_t)(m0 + row1) * DD + (k0) + cs1],                 \
                    smem + (buf) * 8192 + f1);                                 \
        gload_lds16(&W[(size_t)(n0 + row0) * DD + (k0) + cs0],                 \
                    smem + 16384 + (buf) * 8192 + f0);                         \
        gload_lds16(&W[(size_t)(n0 + row1) * DD + (k0) + cs1],                 \
                    smem + 16384 + (buf) * 8192 + f1);                         \
    } while (0)

    f32x4 acc[4][4] = {};

    QKV_STAGE(0, 0);
    __syncthreads();

    int cur = 0;
    for (int k0 = 0; k0 < DD; k0 += 32) {
        if (k0 + 32 < DD) QKV_STAGE(k0 + 32, cur ^ 1);

        const char* Ab = smem + cur * 8192;
        const char* Bb = smem + 16384 + cur * 8192;
        v8s af[4], bf[4];
#pragma unroll
        for (int i = 0; i < 4; ++i)
            af[i] = *(const v8s*)(Ab + (wm + (i << 4) + l15) * 64 + (quad << 4));
#pragma unroll
        for (int j = 0; j < 4; ++j)
            bf[j] = *(const v8s*)(Bb + (wn + (j << 4) + l15) * 64 + (quad << 4));
#pragma unroll
        for (int i = 0; i < 4; ++i)
#pragma unroll
            for (int j = 0; j < 4; ++j)
                acc[i][j] = __builtin_amdgcn_mfma_f32_16x16x32_bf16(af[i], bf[j], acc[i][j], 0, 0, 0);

        __syncthreads();
        cur ^= 1;
    }
#undef QKV_STAGE

    if (which == 2) {
#pragma unroll
        for (int i = 0; i < 4; ++i)
#pragma unroll
            for (int j = 0; j < 4; ++j) {
                const int n = n0 + wn + (j << 4) + l15;
                const int h = n >> 6, hd = n & 63;
                const int mb = m0 + wm + (i << 4) + (quad << 2);
                const int b = mb >> 11, t = mb & 2047;
                ushort4 pk;
                pk.x = f2bf(acc[i][j][0]); pk.y = f2bf(acc[i][j][1]);
                pk.z = f2bf(acc[i][j][2]); pk.w = f2bf(acc[i][j][3]);
                *(ushort4*)&vo[((((size_t)(b * NH + h) << 6) + hd) << 11) + t] = pk;
            }
    } else {
        unsigned short* outp = (which == 0) ? qo : ko;
        const float sc = (which == 1) ? 0.125f : 1.0f;
#pragma unroll
        for (int p = 0; p < 2; ++p) {
            __syncthreads();
            if ((wid >> 1) == p) {
#pragma unroll
                for (int i = 0; i < 4; ++i)
#pragma unroll
                    for (int j = 0; j < 4; ++j)
#pragma unroll
                        for (int r = 0; r < 4; ++r) {
                            const int row = (i << 4) + (quad << 2) + r;
                            SMEM[row * 136 + wn + (j << 4) + l15] = f2bf(acc[i][j][r] * sc);
                        }
            }
            __syncthreads();
            const int rr = tid >> 2;
            const int cg = (tid & 3) << 5;
            const int m = m0 + (p << 6) + rr;
            const int b = m >> 11, t = m & 2047;
#pragma unroll
            for (int k2 = 0; k2 < 4; ++k2) {
                const int n = n0 + cg + (k2 << 3);
                const int h = n >> 6, hd = n & 63;
                const uint4 val = *(const uint4*)&SMEM[rr * 136 + cg + (k2 << 3)];
                *(uint4*)&outp[(((size_t)(b * NH + h) * TT + t) << 6) + hd] = val;
            }
        }
    }
}

// ============================================================================
// Flash attention (kept from R10): S^T formulation, XCD swizzle, unpaired
// longest-first grid, single-barrier double-buffered K/V staging, and the
// Vts column XOR-swizzle by row-bit-3 (targets the measured 2-way conflict
// on the Vt v4s PV reads; K/Q b128 reads and writes stay uniform).
// ============================================================================
__global__ __launch_bounds__(256) void attn_mfma(
    const unsigned short* __restrict__ q, const unsigned short* __restrict__ k,
    const unsigned short* __restrict__ vt, unsigned short* __restrict__ ctx)
{
    __shared__ unsigned short Qs[64][72];
    __shared__ unsigned short Ks[2][64][72];
    __shared__ unsigned short Vts[2][64][72];

    const int tid = threadIdx.x;
    const int lane = tid & 63;
    const int wid = tid >> 6;
    const int l15 = lane & 15, quad = lane >> 4;

    // bx = bh (XCD-locality: lin = bh + 32*by => lin%8 = bh%8), by -> q-tile
    const int bh = blockIdx.x;
    const int qt = 31 - (int)blockIdx.y;      // longest blocks dispatch first
    const int q0 = qt << 6;
    const int qrow = q0 + (wid << 4) + l15;   // this lane's q-row

    const unsigned short* qb = q + (size_t)bh * TT * HDD;
    const unsigned short* kb = k + (size_t)bh * TT * HDD;
    const unsigned short* vb = vt + (size_t)bh * HDD * TT;   // (HD, T)
    unsigned short* cb = ctx + (size_t)bh * TT * HDD;

    const int cr = tid >> 3;            // staging row 0..31 (x2 rounds)
    const int cc = (tid & 7) << 3;      // staging col (ushort), 16B chunks
    const int vsw = (cr & 8) << 2;      // Vts write swizzle (row-bit-3)
    const int ccv = cc ^ vsw;
    const int rsw = (l15 & 8) << 2;     // Vts read swizzle for this lane

    // Q tile + K/V tile 0 -> LDS
#pragma unroll
    for (int u = 0; u < 2; ++u) {
        const int r = cr + (u << 5);
        *(uint4*)&Qs[r][cc] = *(const uint4*)&qb[(size_t)(q0 + r) * HDD + cc];
    }
    {
        uint4 k0r = *(const uint4*)&kb[(size_t)cr * HDD + cc];
        uint4 k1r = *(const uint4*)&kb[(size_t)(cr + 32) * HDD + cc];
        uint4 v0r = *(const uint4*)&vb[((size_t)cr << 11) + cc];
        uint4 v1r = *(const uint4*)&vb[((size_t)(cr + 32) << 11) + cc];
        *(uint4*)&Ks[0][cr][cc] = k0r;
        *(uint4*)&Ks[0][cr + 32][cc] = k1r;
        *(uint4*)&Vts[0][cr][ccv] = v0r;
        *(uint4*)&Vts[0][cr + 32][ccv] = v1r;
    }
    __syncthreads();

    // Q B-frags, wave-resident for the k-loop
    v8s qf[2];
#pragma unroll
    for (int c = 0; c < 2; ++c)
        qf[c] = *(const v8s*)&Qs[(wid << 4) + l15][(c << 5) + (quad << 3)];

    float m_i = -INFINITY, l_i = 0.f;
    f32x4 o[4] = {};                    // O^T: d = m*16 + quad*4 + r, col q=l15

    for (int jt = 0; jt <= qt; ++jt) {
        const int cur = jt & 1;

        // issue global loads for tile jt+1 (land during compute below)
        uint4 k0r, k1r, v0r, v1r;
        const bool pre = (jt < qt);
        if (pre) {
            const int kn = (jt + 1) << 6;
            k0r = *(const uint4*)&kb[(size_t)(kn + cr) * HDD + cc];
            k1r = *(const uint4*)&kb[(size_t)(kn + cr + 32) * HDD + cc];
            v0r = *(const uint4*)&vb[((size_t)cr << 11) + kn + cc];
            v1r = *(const uint4*)&vb[((size_t)(cr + 32) << 11) + kn + cc];
        }

        const int k0 = jt << 6;

        // S^T = K . Q^T : St[k = m*16+quad*4+r][q = l15]  (K pre-scaled)
        f32x4 s[4] = {};
#pragma unroll
        for (int m = 0; m < 4; ++m) {
            const v8s kf0 = *(const v8s*)&Ks[cur][(m << 4) + l15][quad << 3];
            const v8s kf1 = *(const v8s*)&Ks[cur][(m << 4) + l15][32 + (quad << 3)];
            s[m] = __builtin_amdgcn_mfma_f32_16x16x32_bf16(kf0, qf[0], s[m], 0, 0, 0);
            s[m] = __builtin_amdgcn_mfma_f32_16x16x32_bf16(kf1, qf[1], s[m], 0, 0, 0);
        }

        if (jt == qt) {                 // causal mask, diagonal tile only
#pragma unroll
            for (int m = 0; m < 4; ++m) {
                const int kc = k0 + (m << 4) + (quad << 2);
#pragma unroll
                for (int r = 0; r < 4; ++r)
                    if (kc + r > qrow) s[m][r] = -INFINITY;
            }
        }

        // online softmax: one q-row per lane (16 in-reg values, 2 shfl)
        float mx = fmaxf(fmaxf(s[0][0], s[0][1]), fmaxf(s[0][2], s[0][3]));
        mx = fmaxf(mx, fmaxf(fmaxf(s[1][0], s[1][1]), fmaxf(s[1][2], s[1][3])));
        mx = fmaxf(mx, fmaxf(fmaxf(s[2][0], s[2][1]), fmaxf(s[2][2], s[2][3])));
        mx = fmaxf(mx, fmaxf(fmaxf(s[3][0], s[3][1]), fmaxf(s[3][2], s[3][3])));
        mx = fmaxf(mx, __shfl_xor(mx, 16));
        mx = fmaxf(mx, __shfl_xor(mx, 32));
        const float m_new = fmaxf(m_i, mx);
        const float alpha = __expf(m_i - m_new);
        m_i = m_new;

        float sum = 0.f;
        v4s pf[4];
#pragma unroll
        for (int m = 0; m < 4; ++m) {
            const float p0 = __expf(s[m][0] - m_new);
            const float p1 = __expf(s[m][1] - m_new);
            const float p2 = __expf(s[m][2] - m_new);
            const float p3 = __expf(s[m][3] - m_new);
            sum += (p0 + p1) + (p2 + p3);
            pf[m] = pack_bf16x4(p0, p1, p2, p3);
        }
        sum += __shfl_xor(sum, 16);
        sum += __shfl_xor(sum, 32);
        l_i = l_i * alpha + sum;

#pragma unroll
        for (int m = 0; m < 4; ++m)
#pragma unroll
            for (int r = 0; r < 4; ++r)
                o[m][r] *= alpha;

        // O^T += Vt . P^T   (A = Vt 16x16 chunk (swizzled read), B = P^T regs)
#pragma unroll
        for (int m = 0; m < 4; ++m)
#pragma unroll
            for (int c = 0; c < 4; ++c) {
                const v4s vf = *(const v4s*)&Vts[cur][(m << 4) + l15]
                                                    [(((c << 4) + (quad << 2)) ^ rsw)];
                o[m] = mfma16x16x16bf16(vf, pf[c], o[m]);
            }

        // publish tile jt+1 into the other buffer
        if (pre) {
            const int nxt = cur ^ 1;
            *(uint4*)&Ks[nxt][cr][cc] = k0r;
            *(uint4*)&Ks[nxt][cr + 32][cc] = k1r;
            *(uint4*)&Vts[nxt][cr][ccv] = v0r;
            *(uint4*)&Vts[nxt][cr + 32][ccv] = v1r;
        }
        __syncthreads();
    }

    // normalize + store: ctx[q][d], d = m*16 + quad*4 + r (8B stores)
    const float linv = 1.f / l_i;
#pragma unroll
    for (int m = 0; m < 4; ++m) {
        ushort4 st;
        st.x = f2bf(o[m][0] * linv); st.y = f2bf(o[m][1] * linv);
        st.z = f2bf(o[m][2] * linv); st.w = f2bf(o[m][3] * linv);
        *(ushort4*)&cb[((size_t)qrow << 6) + (m << 4) + (quad << 2)] = st;
    }
}

// ============================================================================
// Output projection: REVERTED to R6's global_load_lds double-buffered K-loop.
// ============================================================================
__global__ __launch_bounds__(256) void oproj_mfma(
    const unsigned short* __restrict__ c, const unsigned short* __restrict__ wo,
    const float* __restrict__ bo, float* __restrict__ out)
{
    __shared__ unsigned short SMEM[16384];    // 32 KB

    const int tid = threadIdx.x;
    const int lane = tid & 63;
    const int wid = tid >> 6;
    const int l15 = lane & 15, quad = lane >> 4;

    const int m0 = blockIdx.x << 7;
    const int n0 = blockIdx.y << 7;
    const int wm = (wid >> 1) << 6, wn = (wid & 1) << 6;

    const int f0 = (wid << 11) + (lane << 4);
    const int row0 = f0 >> 6, cs0 = (f0 & 63) >> 1;
    const int f1 = f0 + 1024;
    const int row1 = f1 >> 6, cs1 = (f1 & 63) >> 1;

    char* const smem = (char*)SMEM;

#define OP_STAGE(k0, buf)                                                      \
    do {                                                                       \
        gload_lds16(&c[(size_t)(m0 + row0) * DD + (k0) + cs0],                 \
                    smem + (buf) * 8192 + f0);                                 \
        gload_lds16(&c[(size_t)(m0 + row1) * DD + (k0) + cs1],                 \
                    smem + (buf) * 8192 + f1);                                 \
        gload_lds16(&wo[(size_t)(n0 + row0) * DD + (k0) + cs0],                \
                    smem + 16384 + (buf) * 8192 + f0);                         \
        gload_lds16(&wo[(size_t)(n0 + row1) * DD + (k0) + cs1],                \
                    smem + 16384 + (buf) * 8192 + f1);                         \
    } while (0)

    f32x4 acc[4][4] = {};

    OP_STAGE(0, 0);
    __syncthreads();

    int cur = 0;
    for (int k0 = 0; k0 < DD; k0 += 32) {
        if (k0 + 32 < DD) OP_STAGE(k0 + 32, cur ^ 1);

        const char* Ab = smem + cur * 8192;
        const char* Bb = smem + 16384 + cur * 8192;
        v8s af[4], bf[4];
#pragma unroll
        for (int i = 0; i < 4; ++i)
            af[i] = *(const v8s*)(Ab + (wm + (i << 4) + l15) * 64 + (quad << 4));
#pragma unroll
        for (int j = 0; j < 4; ++j)
            bf[j] = *(const v8s*)(Bb + (wn + (j << 4) + l15) * 64 + (quad << 4));
#pragma unroll
        for (int i = 0; i < 4; ++i)
#pragma unroll
            for (int j = 0; j < 4; ++j)
                acc[i][j] = __builtin_amdgcn_mfma_f32_16x16x32_bf16(af[i], bf[j], acc[i][j], 0, 0, 0);

        __syncthreads();
        cur ^= 1;
    }
#undef OP_STAGE

#pragma unroll
    for (int j = 0; j < 4; ++j) {
        const int n = n0 + wn + (j << 4) + l15;
        const float bias = bo[n];
#pragma unroll
        for (int i = 0; i < 4; ++i) {
            const int mb = m0 + wm + (i << 4) + (quad << 2);
#pragma unroll
            for (int r = 0; r < 4; ++r)
                out[(size_t)(mb + r) * DD + n] = acc[i][j][r] + bias;
        }
    }
}

extern "C" void kernel_launch(void* const* d_in, const int* in_sizes, int n_in,
                              void* d_out, int out_size, void* d_ws, size_t ws_size,
                              hipStream_t stream) {
    const float* x  = (const float*)d_in[0];
    const float* Wq = (const float*)d_in[1];
    const float* Wk = (const float*)d_in[2];
    const float* Wv = (const float*)d_in[3];
    const float* Wo = (const float*)d_in[4];
    const float* bo = (const float*)d_in[5];
    float* out = (float*)d_out;

    const size_t NX = (size_t)BB * TT * DD;
    const size_t NW = (size_t)DD * DD;

    unsigned short* xb  = (unsigned short*)d_ws;
    unsigned short* wqb = xb + NX;
    unsigned short* wkb = wqb + NW;
    unsigned short* wvb = wkb + NW;
    unsigned short* wob = wvb + NW;
    unsigned short* qb  = wob + NW;
    unsigned short* kb  = qb + NX;
    unsigned short* vtb = kb + NX;
    unsigned short* cbuf = vtb + NX;

    cast5_kernel<<<dim3(4096, 5), 256, 0, stream>>>(x, Wq, Wk, Wv, Wo,
                                                    xb, wqb, wkb, wvb, wob);
    qkv_mfma<<<dim3(32, 24), 256, 0, stream>>>(xb, wqb, wkb, wvb, qb, kb, vtb);
    attn_mfma<<<dim3(32, 32), 256, 0, stream>>>(qb, kb, vtb, cbuf);
    oproj_mfma<<<dim3(32, 8), 256, 0, stream>>>(cbuf, wob, bo, out);
}